// Round 1
// baseline (386.833 us; speedup 1.0000x reference)
//
#include <hip/hip_runtime.h>

typedef _Float16 half8 __attribute__((ext_vector_type(8)));
typedef _Float16 half4_t __attribute__((ext_vector_type(4)));
typedef float f32x4 __attribute__((ext_vector_type(4)));

#define ROWS 131072   // B*S = 32*4096
#define D_   256
#define F_   1024

// exact-erf GELU via Abramowitz-Stegun 7.1.26 (|err| <= 1.5e-7)
__device__ __forceinline__ float gelu_erf(float y) {
  float x  = y * 0.70710678118654752440f;
  float ax = fabsf(x);
  float t  = 1.0f / (1.0f + 0.3275911f * ax);
  float poly = ((((1.061405429f * t - 1.453152027f) * t + 1.421413741f) * t
                 - 0.284496736f) * t + 0.254829592f) * t;
  float e = __expf(-ax * ax);
  float erfv = copysignf(1.0f - poly * e, x);
  return 0.5f * y * (1.0f + erfv);
}

// ---------------- Kernel 1: residual add + LayerNorm -> fp16 ----------------
__global__ __launch_bounds__(256) void ln_fuse_kernel(
    const float4* __restrict__ xa, const float4* __restrict__ xb,
    const float* __restrict__ gamma, const float* __restrict__ beta,
    half4_t* __restrict__ xn)
{
  const int lane = threadIdx.x & 63;
  const int gw   = (int)((blockIdx.x * blockDim.x + threadIdx.x) >> 6);
  const int nw   = (int)((gridDim.x * blockDim.x) >> 6);
  const float4 g  = ((const float4*)gamma)[lane];
  const float4 be = ((const float4*)beta)[lane];
  for (int row = gw; row < ROWS; row += nw) {
    size_t idx = (size_t)row * 64 + lane;
    float4 a = xa[idx], b = xb[idx];
    float4 v; v.x = a.x + b.x; v.y = a.y + b.y; v.z = a.z + b.z; v.w = a.w + b.w;
    float s  = v.x + v.y + v.z + v.w;
    float s2 = v.x * v.x + v.y * v.y + v.z * v.z + v.w * v.w;
#pragma unroll
    for (int off = 32; off > 0; off >>= 1) {
      s  += __shfl_xor(s,  off, 64);
      s2 += __shfl_xor(s2, off, 64);
    }
    float mean = s * (1.0f / 256.0f);
    float var  = s2 * (1.0f / 256.0f) - mean * mean;
    float rs   = rsqrtf(var + 1e-12f);
    half4_t h;
    h[0] = (_Float16)((v.x - mean) * rs * g.x + be.x);
    h[1] = (_Float16)((v.y - mean) * rs * g.y + be.y);
    h[2] = (_Float16)((v.z - mean) * rs * g.z + be.z);
    h[3] = (_Float16)((v.w - mean) * rs * g.w + be.w);
    xn[idx] = h;
  }
}

// ---------------- Kernel 1b: W fp32 -> fp16 ----------------
__global__ __launch_bounds__(256) void wconv_kernel(
    const float4* __restrict__ W, half4_t* __restrict__ Wh)
{
  int i = blockIdx.x * 256 + threadIdx.x;  // 65536 threads cover 262144 floats
  float4 f = W[i];
  half4_t h;
  h[0] = (_Float16)f.x; h[1] = (_Float16)f.y;
  h[2] = (_Float16)f.z; h[3] = (_Float16)f.w;
  Wh[i] = h;
}

// ---------------- Kernel 2: GEMM (A[M,256] * W[1024,256]^T) + bias + GELU ----
// 128x128 tile, BK=64, 4 waves (2x2), double-buffered LDS via global_load_lds.
__global__ __launch_bounds__(256, 2) void gemm_kernel(
    const _Float16* __restrict__ A, const _Float16* __restrict__ Bw,
    const float* __restrict__ bias, float* __restrict__ out)
{
  __shared__ _Float16 As[2][128 * 64];
  __shared__ _Float16 Bs[2][128 * 64];

  const int bx = blockIdx.x;
  const int mt = bx >> 3, nt = bx & 7;       // 1024 m-tiles x 8 n-tiles
  const size_t m0 = (size_t)mt * 128;
  const int    n0 = nt * 128;
  const int lane = threadIdx.x & 63;
  const int wave = threadIdx.x >> 6;
  const int wm = wave >> 1, wn = wave & 1;

  // per-lane staging source base: lane covers row (lane>>3), 16B chunk (lane&7)
  const _Float16* a_src = A  + (m0 + (size_t)(lane >> 3)) * 256 + (lane & 7) * 8;
  const _Float16* b_src = Bw + ((size_t)n0 + (lane >> 3)) * 256 + (lane & 7) * 8;

  f32x4 acc[4][4] = {};

#define STAGE(buf, k0) do {                                                     \
    _Pragma("unroll")                                                           \
    for (int q = 0; q < 4; ++q) {                                               \
      int c = wave * 4 + q;                                                     \
      __builtin_amdgcn_global_load_lds(                                         \
        (const __attribute__((address_space(1))) void*)(a_src + (size_t)c * 8 * 256 + (k0)), \
        (__attribute__((address_space(3))) void*)(&As[buf][c * 512]), 16, 0, 0);\
      __builtin_amdgcn_global_load_lds(                                         \
        (const __attribute__((address_space(1))) void*)(b_src + (size_t)c * 8 * 256 + (k0)), \
        (__attribute__((address_space(3))) void*)(&Bs[buf][c * 512]), 16, 0, 0);\
    }                                                                           \
  } while (0)

  STAGE(0, 0);

#pragma unroll
  for (int kt = 0; kt < 4; ++kt) {
    const int buf = kt & 1;
    __syncthreads();                  // drains vmcnt(0): staged tile ready
    if (kt < 3) STAGE(buf ^ 1, (kt + 1) * 64);

    const _Float16* abase = &As[buf][(wm * 64 + (lane & 15)) * 64 + (lane >> 4) * 8];
    const _Float16* bbase = &Bs[buf][(wn * 64 + (lane & 15)) * 64 + (lane >> 4) * 8];
#pragma unroll
    for (int kk = 0; kk < 2; ++kk) {
      half8 af[4], bf[4];
#pragma unroll
      for (int i = 0; i < 4; ++i) af[i] = *(const half8*)(abase + i * 16 * 64 + kk * 32);
#pragma unroll
      for (int j = 0; j < 4; ++j) bf[j] = *(const half8*)(bbase + j * 16 * 64 + kk * 32);
#pragma unroll
      for (int i = 0; i < 4; ++i)
#pragma unroll
        for (int j = 0; j < 4; ++j)
          acc[i][j] = __builtin_amdgcn_mfma_f32_16x16x32_f16(af[i], bf[j], acc[i][j], 0, 0, 0);
    }
  }

  // epilogue: bias + exact GELU, fp32 store
  // D mapping (measured, §3): col = lane&15, row = (lane>>4)*4 + reg
  const int r0 = (lane >> 4) * 4;
  const int cc = lane & 15;
#pragma unroll
  for (int j = 0; j < 4; ++j) {
    const int col = n0 + wn * 64 + j * 16 + cc;
    const float bv = bias[col];
#pragma unroll
    for (int i = 0; i < 4; ++i) {
      const size_t row = m0 + (size_t)(wm * 64 + i * 16 + r0);
      float* op = out + row * 1024 + col;
#pragma unroll
      for (int r = 0; r < 4; ++r)
        op[(size_t)r * 1024] = gelu_erf(acc[i][j][r] + bv);
    }
  }
#undef STAGE
}

extern "C" void kernel_launch(void* const* d_in, const int* in_sizes, int n_in,
                              void* d_out, int out_size, void* d_ws, size_t ws_size,
                              hipStream_t stream) {
  const float* x399  = (const float*)d_in[0];
  const float* x365  = (const float*)d_in[1];
  const float* gamma = (const float*)d_in[2];
  const float* beta  = (const float*)d_in[3];
  const float* W     = (const float*)d_in[4];
  const float* bias  = (const float*)d_in[5];
  float* out = (float*)d_out;

  _Float16* xn = (_Float16*)d_ws;                       // 131072*256*2 = 64 MiB
  _Float16* Wh = xn + (size_t)ROWS * D_;                // 1024*256*2  = 512 KiB

  ln_fuse_kernel<<<2048, 256, 0, stream>>>(
      (const float4*)x399, (const float4*)x365, gamma, beta, (half4_t*)xn);
  wconv_kernel<<<256, 256, 0, stream>>>((const float4*)W, (half4_t*)Wh);
  gemm_kernel<<<8192, 256, 0, stream>>>(xn, Wh, bias, out);
}